// Round 19
// baseline (60.243 us; speedup 1.0000x reference)
//
#include <hip/hip_runtime.h>
#include <hip/hip_bf16.h>
#include <math.h>

#define B_   4
#define N_   512
#define DIN  256
#define E_   64
#define H_   4

typedef __attribute__((ext_vector_type(8))) short bf16x8;
typedef __attribute__((ext_vector_type(8))) unsigned short u16x8;
typedef __attribute__((ext_vector_type(4))) float f32x4;

__device__ __forceinline__ unsigned short f2bf(float f) {
    __hip_bfloat16 h = __float2bfloat16(f);
    return *reinterpret_cast<unsigned short*>(&h);
}
// slot (0..15) -> bh, XCD-locality perm: slot%8 = XCD, pairs (2s, 2s+1) per XCD
__device__ __forceinline__ int slot2bh(int slot) {
    return ((slot & 7) << 1) | (slot >> 3);
}

// ---------------------------------------------------------------------------
// Projection (R17-identical: R9 body + XCD swizzle + h==2-only f32 stores).
// ---------------------------------------------------------------------------
__global__ __launch_bounds__(256) void proj_kernel(
    const float* __restrict__ x,
    const float* __restrict__ Wq, const float* __restrict__ bq,
    const float* __restrict__ Wk, const float* __restrict__ bk,
    const float* __restrict__ Wv, const float* __restrict__ bv,
    float* __restrict__ Q, float* __restrict__ KT,
    float* __restrict__ qn2, float* __restrict__ kn2,
    unsigned short* __restrict__ QF, unsigned short* __restrict__ KF,
    unsigned short* __restrict__ VF)
{
    const int tid = threadIdx.x;
    const int slot = blockIdx.x & 15;
    const int rest = blockIdx.x >> 4;      // 0..47
    const int tile = rest & 15;
    const int p    = rest >> 4;            // 0..2
    const int bhid = slot2bh(slot);
    const int h = bhid & 3;
    const int b = bhid >> 2;

    const float* W;
    const float* bias;
    if (p == 0)      { W = Wq; bias = bq; }
    else if (p == 1) { W = Wk; bias = bk; }
    else             { W = Wv; bias = bv; }
    W    += (size_t)h * DIN * E_;
    bias += h * E_;

    const int rowbase = tile * 32;
    const float* xb = x + ((size_t)b * N_ + rowbase) * DIN;

    __shared__ float XsT[64][34];
    __shared__ float Ws[64][64];
    __shared__ float Ys[64][33];
    __shared__ unsigned short Vst[64][48];

    const int tr = tid >> 4;
    const int tc = tid & 15;

    float acc[2][4];
    #pragma unroll
    for (int i = 0; i < 2; ++i)
        #pragma unroll
        for (int j = 0; j < 4; ++j) acc[i][j] = 0.f;

    for (int dc = 0; dc < DIN; dc += 64) {
        for (int l = tid; l < 2048; l += 256) {
            int r = l >> 6, d = l & 63;
            XsT[d][r] = xb[r * DIN + dc + d];
        }
        {
            const float4* Wg4 = (const float4*)(W + (size_t)dc * E_);
            #pragma unroll
            for (int i = 0; i < 4; ++i) ((float4*)Ws)[tid + i * 256] = Wg4[tid + i * 256];
        }
        __syncthreads();

        #pragma unroll 8
        for (int d = 0; d < 64; ++d) {
            float2 xv = *(const float2*)&XsT[d][tr * 2];
            float4 wv = *(const float4*)&Ws[d][tc * 4];
            acc[0][0] = fmaf(xv.x, wv.x, acc[0][0]);
            acc[0][1] = fmaf(xv.x, wv.y, acc[0][1]);
            acc[0][2] = fmaf(xv.x, wv.z, acc[0][2]);
            acc[0][3] = fmaf(xv.x, wv.w, acc[0][3]);
            acc[1][0] = fmaf(xv.y, wv.x, acc[1][0]);
            acc[1][1] = fmaf(xv.y, wv.y, acc[1][1]);
            acc[1][2] = fmaf(xv.y, wv.z, acc[1][2]);
            acc[1][3] = fmaf(xv.y, wv.w, acc[1][3]);
        }
        __syncthreads();
    }

    const size_t bh = (size_t)bhid;
    float4 bias4 = *(const float4*)&bias[tc * 4];
    float v0[4], v1[4];
    v0[0] = acc[0][0] + bias4.x; v0[1] = acc[0][1] + bias4.y;
    v0[2] = acc[0][2] + bias4.z; v0[3] = acc[0][3] + bias4.w;
    v1[0] = acc[1][0] + bias4.x; v1[1] = acc[1][1] + bias4.y;
    v1[2] = acc[1][2] + bias4.z; v1[3] = acc[1][3] + bias4.w;

    const int r0 = rowbase + tr * 2;

    if (p < 2) {
        float s0 = 0.f, s1 = 0.f;
        #pragma unroll
        for (int j = 0; j < 4; ++j) {
            s0 = fmaf(v0[j], v0[j], s0);
            s1 = fmaf(v1[j], v1[j], s1);
        }
        #pragma unroll
        for (int off = 1; off < 16; off <<= 1) {
            s0 += __shfl_xor(s0, off, 64);
            s1 += __shfl_xor(s1, off, 64);
        }
        if (tc == 0) {
            float* nrm = (p == 0) ? qn2 : kn2;
            nrm[bh * N_ + r0]     = s0;
            nrm[bh * N_ + r0 + 1] = s1;
        }
        unsigned short* f = ((p == 0) ? QF : KF) + bh * (size_t)(N_ * E_);
        const int t_ = r0 >> 4, li = r0 & 15;
        const int gg = tc >> 1, j0 = (tc & 1) * 4;
        ushort4 u0, u1;
        u0.x = f2bf(v0[0]); u0.y = f2bf(v0[1]); u0.z = f2bf(v0[2]); u0.w = f2bf(v0[3]);
        u1.x = f2bf(v1[0]); u1.y = f2bf(v1[1]); u1.z = f2bf(v1[2]); u1.w = f2bf(v1[3]);
        *(ushort4*)&f[(size_t)((t_ * 8 + gg) * 16 + li) * 8 + j0]       = u0;
        *(ushort4*)&f[(size_t)((t_ * 8 + gg) * 16 + li + 1) * 8 + j0]   = u1;
    }

    if (p == 0) {
        if (h == 2) {      // f32 Q needed only by the L1 head
            float* o = Q + bh * (size_t)(N_ * E_);
            *(float4*)&o[(size_t)r0 * E_ + tc * 4]       = make_float4(v0[0], v0[1], v0[2], v0[3]);
            *(float4*)&o[(size_t)(r0 + 1) * E_ + tc * 4] = make_float4(v1[0], v1[1], v1[2], v1[3]);
        }
    } else if (p == 1) {
        if (h == 2) {      // f32 KT needed only by the L1 head
            #pragma unroll
            for (int j = 0; j < 4; ++j) {
                Ys[tc * 4 + j][tr * 2]     = v0[j];
                Ys[tc * 4 + j][tr * 2 + 1] = v1[j];
            }
            __syncthreads();
            const int e  = tid >> 2;
            const int n0 = (tid & 3) * 8;
            float* o = KT + bh * (size_t)(E_ * N_) + (size_t)e * N_ + rowbase + n0;
            float4 a, c;
            a.x = Ys[e][n0 + 0]; a.y = Ys[e][n0 + 1];
            a.z = Ys[e][n0 + 2]; a.w = Ys[e][n0 + 3];
            c.x = Ys[e][n0 + 4]; c.y = Ys[e][n0 + 5];
            c.z = Ys[e][n0 + 6]; c.w = Ys[e][n0 + 7];
            *(float4*)&o[0] = a;
            *(float4*)&o[4] = c;
        }
    } else {
        #pragma unroll
        for (int j = 0; j < 4; ++j) {
            Vst[tc * 4 + j][tr * 2]     = f2bf(v0[j]);
            Vst[tc * 4 + j][tr * 2 + 1] = f2bf(v1[j]);
        }
        __syncthreads();
        const int et = tid >> 6, g = (tid >> 4) & 3, li = tid & 15;
        u16x8 wv8 = *(const u16x8*)&Vst[et * 16 + li][g * 8];
        *(u16x8*)&VF[bh * (size_t)(N_ * E_)
                     + (size_t)((((tile * 4 + et) * 4 + g) * 16) + li) * 8] = wv8;
    }
}

// ---------------------------------------------------------------------------
// attn_partial (R17 + controlled operand hoists):
//  - V frags (4x b128) issued at kernel top (before logits).
//  - K frags for BOTH 16-key tiles + norms issued at logits entry.
//  - L1 head: f32 path unchanged except k-load unroll 4->8.
// ---------------------------------------------------------------------------
template <int HEAD>
__device__ __forceinline__ void mfma_logits32(
    int w, int kh, int lane, size_t bh, int qt, int q0, int pid,
    const unsigned short* __restrict__ QF,
    const unsigned short* __restrict__ KF,
    const float* __restrict__ qn2, const float* __restrict__ kn2,
    char* Pw, float* __restrict__ Mpart, float* __restrict__ Spart)
{
    const int g = lane >> 4, li = lane & 15;
    const int row0 = g * 4;
    const unsigned short* qfb = QF + bh * (N_ * E_) + (size_t)qt * 1024;
    const unsigned short* kfb = KF + bh * (N_ * E_);
    const int kt0 = (kh * 4 + w) * 2;

    // ---- issue all QK operand loads upfront (max loads in flight) ----
    bf16x8 a0  = *(const bf16x8*)&qfb[(g * 16 + li) * 8];
    bf16x8 a1  = *(const bf16x8*)&qfb[((g + 4) * 16 + li) * 8];
    bf16x8 b00 = *(const bf16x8*)&kfb[(size_t)((kt0 * 8 + g) * 16 + li) * 8];
    bf16x8 b01 = *(const bf16x8*)&kfb[(size_t)((kt0 * 8 + g + 4) * 16 + li) * 8];
    bf16x8 b10 = *(const bf16x8*)&kfb[(size_t)(((kt0 + 1) * 8 + g) * 16 + li) * 8];
    bf16x8 b11 = *(const bf16x8*)&kfb[(size_t)(((kt0 + 1) * 8 + g + 4) * 16 + li) * 8];
    float kc0 = 0.f, kc1 = 0.f;
    if (HEAD == 1 || HEAD == 3) {
        kc0 = kn2[bh * N_ + kt0 * 16 + li];
        kc1 = kn2[bh * N_ + (kt0 + 1) * 16 + li];
    }
    float qrow[4];
    if (HEAD == 1) {
        #pragma unroll
        for (int j = 0; j < 4; ++j) qrow[j] = rsqrtf(qn2[bh * N_ + q0 + row0 + j]);
    } else if (HEAD == 3) {
        #pragma unroll
        for (int j = 0; j < 4; ++j) qrow[j] = qn2[bh * N_ + q0 + row0 + j];
    }

    f32x4 acca = {0.f, 0.f, 0.f, 0.f};
    acca = __builtin_amdgcn_mfma_f32_16x16x32_bf16(a0, b00, acca, 0, 0, 0);
    acca = __builtin_amdgcn_mfma_f32_16x16x32_bf16(a1, b01, acca, 0, 0, 0);
    f32x4 accb = {0.f, 0.f, 0.f, 0.f};
    accb = __builtin_amdgcn_mfma_f32_16x16x32_bf16(a0, b10, accb, 0, 0, 0);
    accb = __builtin_amdgcn_mfma_f32_16x16x32_bf16(a1, b11, accb, 0, 0, 0);

    float lg[2][4];
    #pragma unroll
    for (int j = 0; j < 4; ++j) {
        float da = acca[j], db = accb[j];
        if (HEAD == 0)      { lg[0][j] = da * 0.125f; lg[1][j] = db * 0.125f; }
        else if (HEAD == 1) { float rq = qrow[j];
                              lg[0][j] = da * rq * rsqrtf(kc0);
                              lg[1][j] = db * rq * rsqrtf(kc1); }
        else                { lg[0][j] = -sqrtf(fmaxf(qrow[j] + kc0 - 2.f * da, 0.f));
                              lg[1][j] = -sqrtf(fmaxf(qrow[j] + kc1 - 2.f * db, 0.f)); }
    }

    float mx[4];
    #pragma unroll
    for (int j = 0; j < 4; ++j) {
        float m = fmaxf(lg[0][j], lg[1][j]);
        #pragma unroll
        for (int off = 1; off < 16; off <<= 1) m = fmaxf(m, __shfl_xor(m, off, 64));
        mx[j] = m;
    }

    float sm[4] = {0.f, 0.f, 0.f, 0.f};
    #pragma unroll
    for (int t = 0; t < 2; ++t) {
        #pragma unroll
        for (int j = 0; j < 4; ++j) {
            const int row = row0 + j;
            float pv = __expf(lg[t][j] - mx[j]);
            sm[j] += pv;
            const int byte = (row * 64 + (t * 16 + li) * 2) ^ ((row & 7) << 4);
            *(unsigned short*)(Pw + byte) = f2bf(pv);
        }
    }
    #pragma unroll
    for (int j = 0; j < 4; ++j) {
        float s = sm[j];
        #pragma unroll
        for (int off = 1; off < 16; off <<= 1) s += __shfl_xor(s, off, 64);
        if (li == 0) {
            Mpart[(size_t)pid * 16 + row0 + j] = mx[j];
            Spart[(size_t)pid * 16 + row0 + j] = s;
        }
    }
}

__global__ __launch_bounds__(256) void attn_partial(
    const float* __restrict__ Qf, const float* __restrict__ KT,
    const unsigned short* __restrict__ QF, const unsigned short* __restrict__ KF,
    const unsigned short* __restrict__ VF,
    const float* __restrict__ qn2, const float* __restrict__ kn2,
    float* __restrict__ Opart, float* __restrict__ Mpart,
    float* __restrict__ Spart)
{
    const int tid  = threadIdx.x;
    const int w    = tid >> 6;
    const int lane = tid & 63;
    const int slot  = blockIdx.x & 15;
    const int inner = blockIdx.x >> 4;     // 0..127
    const int kh = inner & 3;
    const int qt = inner >> 2;
    const int bhid = slot2bh(slot);
    const size_t bhs = (size_t)bhid;
    const int q0 = qt * 16;
    const int pid = bhid * 512 + qt * 16 + kh * 4 + w;
    const int kb = kh * 4 + w;

    __shared__ unsigned short Plds[4][512];
    __shared__ float q_lds[16][68];

    const int g = lane >> 4, li = lane & 15;
    char* Pw = (char*)&Plds[w][0];
    const int h = bhid & 3;

    // ---- hoist V fragment loads (used after softmax; ~2000 cyc to cover) ----
    bf16x8 vb[4];
    {
        const unsigned short* vfb = VF + bhs * (N_ * E_);
        #pragma unroll
        for (int et = 0; et < 4; ++et)
            vb[et] = *(const bf16x8*)&vfb[(size_t)((((kb * 4 + et) * 4 + g) * 16) + li) * 8];
    }

    if (h == 2) {
        {
            const int r = tid >> 4, c0 = (tid & 15) * 4;
            *(float4*)&q_lds[r][c0] =
                *(const float4*)&Qf[bhs * (N_ * E_) + (size_t)(q0 + r) * E_ + c0];
        }
        __syncthreads();

        const int half = lane >> 5;
        const int kloc = lane & 31;
        const int key  = kh * 128 + w * 32 + kloc;
        const float* kp = KT + bhs * (E_ * N_) + key;

        float acc[8];
        #pragma unroll
        for (int i = 0; i < 8; ++i) acc[i] = 0.f;

        #pragma unroll 8
        for (int ec = 0; ec < 16; ++ec) {
            float k0 = kp[(size_t)(ec * 4 + 0) * N_];
            float k1 = kp[(size_t)(ec * 4 + 1) * N_];
            float k2 = kp[(size_t)(ec * 4 + 2) * N_];
            float k3 = kp[(size_t)(ec * 4 + 3) * N_];
            #pragma unroll
            for (int i = 0; i < 8; ++i) {
                float4 q4 = *(const float4*)&q_lds[half * 8 + i][ec * 4];
                acc[i] += fabsf(k0 - q4.x) + fabsf(k1 - q4.y)
                        + fabsf(k2 - q4.z) + fabsf(k3 - q4.w);
            }
        }

        #pragma unroll
        for (int i = 0; i < 8; ++i) {
            const int row = half * 8 + i;
            float mn = acc[i];
            #pragma unroll
            for (int off = 1; off < 32; off <<= 1) mn = fminf(mn, __shfl_xor(mn, off, 64));
            float p = __expf(mn - acc[i]);
            float s = p;
            #pragma unroll
            for (int off = 1; off < 32; off <<= 1) s += __shfl_xor(s, off, 64);
            const int byte = (row * 64 + kloc * 2) ^ ((row & 7) << 4);
            *(unsigned short*)(Pw + byte) = f2bf(p);
            if (kloc == 0) {
                Mpart[(size_t)pid * 16 + row] = -mn;
                Spart[(size_t)pid * 16 + row] = s;
            }
        }
    } else if (h == 0) {
        mfma_logits32<0>(w, kh, lane, bhs, qt, q0, pid, QF, KF, qn2, kn2, Pw, Mpart, Spart);
    } else if (h == 1) {
        mfma_logits32<1>(w, kh, lane, bhs, qt, q0, pid, QF, KF, qn2, kn2, Pw, Mpart, Spart);
    } else {
        mfma_logits32<3>(w, kh, lane, bhs, qt, q0, pid, QF, KF, qn2, kn2, Pw, Mpart, Spart);
    }
    __syncthreads();

    {
        const int byte = (li * 64 + g * 16) ^ ((li & 7) << 4);
        bf16x8 pa = *(const bf16x8*)(Pw + byte);
        #pragma unroll
        for (int et = 0; et < 4; ++et) {
            f32x4 acc = {0.f, 0.f, 0.f, 0.f};
            acc = __builtin_amdgcn_mfma_f32_16x16x32_bf16(pa, vb[et], acc, 0, 0, 0);
            *(f32x4*)&Opart[(size_t)pid * 1024 + ((et * 4 + g) * 16 + li) * 4] = acc;
        }
    }
}

// ---------------------------------------------------------------------------
// combine (R17-identical).
// ---------------------------------------------------------------------------
__global__ __launch_bounds__(256) void combine_kernel(
    const float* __restrict__ Opart, const float* __restrict__ Mpart,
    const float* __restrict__ Spart, float* __restrict__ out)
{
    const int tid = threadIdx.x;
    const int slot = blockIdx.x & 15;
    const int qt   = blockIdx.x >> 4;
    const int bhid = slot2bh(slot);
    const int b = bhid >> 2, h = bhid & 3;
    const int base = (bhid * 32 + qt) * 16;

    __shared__ float ms[16][16], ss[16][16], wls[16][16];
    __shared__ float sginv[16];
    __shared__ float Ot[16][68];

    {
        const int p = tid >> 4, row = tid & 15;
        ms[p][row] = Mpart[(size_t)(base + p) * 16 + row];
        ss[p][row] = Spart[(size_t)(base + p) * 16 + row];
    }
    __syncthreads();
    {
        const int p = tid >> 4, row = tid & 15;
        float mg = ms[0][row];
        #pragma unroll
        for (int q = 1; q < 16; ++q) mg = fmaxf(mg, ms[q][row]);
        wls[p][row] = __expf(ms[p][row] - mg);
    }
    __syncthreads();
    if (tid < 16) {
        float s = 0.f;
        #pragma unroll
        for (int p = 0; p < 16; ++p) s += wls[p][tid] * ss[p][tid];
        sginv[tid] = 1.f / s;
    }
    __syncthreads();

    {
        const int et = tid >> 6, g = (tid >> 4) & 3, li = tid & 15;
        float o0 = 0.f, o1 = 0.f, o2 = 0.f, o3 = 0.f;
        const float* op = Opart + (size_t)base * 1024 + ((et * 4 + g) * 16 + li) * 4;
        #pragma unroll
        for (int p = 0; p < 16; ++p) {
            float4 v = *(const float4*)(op + (size_t)p * 1024);
            o0 = fmaf(wls[p][g * 4 + 0], v.x, o0);
            o1 = fmaf(wls[p][g * 4 + 1], v.y, o1);
            o2 = fmaf(wls[p][g * 4 + 2], v.z, o2);
            o3 = fmaf(wls[p][g * 4 + 3], v.w, o3);
        }
        Ot[g * 4 + 0][et * 16 + li] = o0 * sginv[g * 4 + 0];
        Ot[g * 4 + 1][et * 16 + li] = o1 * sginv[g * 4 + 1];
        Ot[g * 4 + 2][et * 16 + li] = o2 * sginv[g * 4 + 2];
        Ot[g * 4 + 3][et * 16 + li] = o3 * sginv[g * 4 + 3];
    }
    __syncthreads();
    {
        const int row = tid >> 4, e0 = (tid & 15) * 4;
        const int n = qt * 16 + row;
        *(float4*)&out[((size_t)b * N_ + n) * (H_ * E_) + h * E_ + e0] =
            *(const float4*)&Ot[row][e0];
    }
}

// ---------------------------------------------------------------------------
extern "C" void kernel_launch(void* const* d_in, const int* in_sizes, int n_in,
                              void* d_out, int out_size, void* d_ws, size_t ws_size,
                              hipStream_t stream)
{
    const float* x  = (const float*)d_in[0];
    const float* Wq = (const float*)d_in[1];
    const float* bq = (const float*)d_in[2];
    const float* Wk = (const float*)d_in[3];
    const float* bk = (const float*)d_in[4];
    const float* Wv = (const float*)d_in[5];
    const float* bv = (const float*)d_in[6];
    float* out = (float*)d_out;

    const size_t qkv = (size_t)B_ * H_ * N_ * E_;   // 524288
    float* Q     = (float*)d_ws;
    float* KT    = Q + qkv;
    float* qn2   = KT + qkv;
    float* kn2   = qn2 + (size_t)B_ * H_ * N_;
    float* Opart = kn2 + (size_t)B_ * H_ * N_;      // 8192 * 1024 f32 = 32 MB
    float* Mpart = Opart + (size_t)8192 * 1024;
    float* Spart = Mpart + (size_t)8192 * 16;
    unsigned short* QF = (unsigned short*)(Spart + (size_t)8192 * 16);
    unsigned short* KF = QF + qkv;
    unsigned short* VF = KF + qkv;

    proj_kernel<<<B_ * H_ * 3 * (N_ / 32), 256, 0, stream>>>(
        x, Wq, bq, Wk, bk, Wv, bv, Q, KT, qn2, kn2, QF, KF, VF);
    attn_partial<<<B_ * H_ * 32 * 4, 256, 0, stream>>>(
        Q, KT, QF, KF, VF, qn2, kn2, Opart, Mpart, Spart);
    combine_kernel<<<B_ * H_ * 32, 256, 0, stream>>>(Opart, Mpart, Spart, out);
}

// Round 20
// 59.013 us; speedup vs baseline: 1.0209x; 1.0209x over previous
//
#include <hip/hip_runtime.h>
#include <hip/hip_bf16.h>
#include <math.h>

#define B_   4
#define N_   512
#define DIN  256
#define E_   64
#define H_   4

typedef __attribute__((ext_vector_type(8))) short bf16x8;
typedef __attribute__((ext_vector_type(8))) unsigned short u16x8;
typedef __attribute__((ext_vector_type(4))) float f32x4;

__device__ __forceinline__ unsigned short f2bf(float f) {
    __hip_bfloat16 h = __float2bfloat16(f);
    return *reinterpret_cast<unsigned short*>(&h);
}
// slot (0..15) -> bh, XCD-locality perm: slot%8 = XCD, pairs (2s, 2s+1) per XCD
__device__ __forceinline__ int slot2bh(int slot) {
    return ((slot & 7) << 1) | (slot >> 3);
}

// ---------------------------------------------------------------------------
// Projection (R9 body + XCD swizzle + h==2-only f32 stores).
// grid = 768: blk = rest*16 + slot; rest = p*16 + tile; bh = slot2bh(slot).
// ---------------------------------------------------------------------------
__global__ __launch_bounds__(256) void proj_kernel(
    const float* __restrict__ x,
    const float* __restrict__ Wq, const float* __restrict__ bq,
    const float* __restrict__ Wk, const float* __restrict__ bk,
    const float* __restrict__ Wv, const float* __restrict__ bv,
    float* __restrict__ Q, float* __restrict__ KT,
    float* __restrict__ qn2, float* __restrict__ kn2,
    unsigned short* __restrict__ QF, unsigned short* __restrict__ KF,
    unsigned short* __restrict__ VF)
{
    const int tid = threadIdx.x;
    const int slot = blockIdx.x & 15;
    const int rest = blockIdx.x >> 4;      // 0..47
    const int tile = rest & 15;
    const int p    = rest >> 4;            // 0..2
    const int bhid = slot2bh(slot);
    const int h = bhid & 3;
    const int b = bhid >> 2;

    const float* W;
    const float* bias;
    if (p == 0)      { W = Wq; bias = bq; }
    else if (p == 1) { W = Wk; bias = bk; }
    else             { W = Wv; bias = bv; }
    W    += (size_t)h * DIN * E_;
    bias += h * E_;

    const int rowbase = tile * 32;
    const float* xb = x + ((size_t)b * N_ + rowbase) * DIN;

    __shared__ float XsT[64][34];
    __shared__ float Ws[64][64];
    __shared__ float Ys[64][33];
    __shared__ unsigned short Vst[64][48];

    const int tr = tid >> 4;
    const int tc = tid & 15;

    float acc[2][4];
    #pragma unroll
    for (int i = 0; i < 2; ++i)
        #pragma unroll
        for (int j = 0; j < 4; ++j) acc[i][j] = 0.f;

    for (int dc = 0; dc < DIN; dc += 64) {
        for (int l = tid; l < 2048; l += 256) {
            int r = l >> 6, d = l & 63;
            XsT[d][r] = xb[r * DIN + dc + d];
        }
        {
            const float4* Wg4 = (const float4*)(W + (size_t)dc * E_);
            #pragma unroll
            for (int i = 0; i < 4; ++i) ((float4*)Ws)[tid + i * 256] = Wg4[tid + i * 256];
        }
        __syncthreads();

        #pragma unroll 8
        for (int d = 0; d < 64; ++d) {
            float2 xv = *(const float2*)&XsT[d][tr * 2];
            float4 wv = *(const float4*)&Ws[d][tc * 4];
            acc[0][0] = fmaf(xv.x, wv.x, acc[0][0]);
            acc[0][1] = fmaf(xv.x, wv.y, acc[0][1]);
            acc[0][2] = fmaf(xv.x, wv.z, acc[0][2]);
            acc[0][3] = fmaf(xv.x, wv.w, acc[0][3]);
            acc[1][0] = fmaf(xv.y, wv.x, acc[1][0]);
            acc[1][1] = fmaf(xv.y, wv.y, acc[1][1]);
            acc[1][2] = fmaf(xv.y, wv.z, acc[1][2]);
            acc[1][3] = fmaf(xv.y, wv.w, acc[1][3]);
        }
        __syncthreads();
    }

    const size_t bh = (size_t)bhid;
    float4 bias4 = *(const float4*)&bias[tc * 4];
    float v0[4], v1[4];
    v0[0] = acc[0][0] + bias4.x; v0[1] = acc[0][1] + bias4.y;
    v0[2] = acc[0][2] + bias4.z; v0[3] = acc[0][3] + bias4.w;
    v1[0] = acc[1][0] + bias4.x; v1[1] = acc[1][1] + bias4.y;
    v1[2] = acc[1][2] + bias4.z; v1[3] = acc[1][3] + bias4.w;

    const int r0 = rowbase + tr * 2;

    if (p < 2) {
        float s0 = 0.f, s1 = 0.f;
        #pragma unroll
        for (int j = 0; j < 4; ++j) {
            s0 = fmaf(v0[j], v0[j], s0);
            s1 = fmaf(v1[j], v1[j], s1);
        }
        #pragma unroll
        for (int off = 1; off < 16; off <<= 1) {
            s0 += __shfl_xor(s0, off, 64);
            s1 += __shfl_xor(s1, off, 64);
        }
        if (tc == 0) {
            float* nrm = (p == 0) ? qn2 : kn2;
            nrm[bh * N_ + r0]     = s0;
            nrm[bh * N_ + r0 + 1] = s1;
        }
        unsigned short* f = ((p == 0) ? QF : KF) + bh * (size_t)(N_ * E_);
        const int t_ = r0 >> 4, li = r0 & 15;
        const int gg = tc >> 1, j0 = (tc & 1) * 4;
        ushort4 u0, u1;
        u0.x = f2bf(v0[0]); u0.y = f2bf(v0[1]); u0.z = f2bf(v0[2]); u0.w = f2bf(v0[3]);
        u1.x = f2bf(v1[0]); u1.y = f2bf(v1[1]); u1.z = f2bf(v1[2]); u1.w = f2bf(v1[3]);
        *(ushort4*)&f[(size_t)((t_ * 8 + gg) * 16 + li) * 8 + j0]       = u0;
        *(ushort4*)&f[(size_t)((t_ * 8 + gg) * 16 + li + 1) * 8 + j0]   = u1;
    }

    if (p == 0) {
        if (h == 2) {      // f32 Q needed only by the L1 head
            float* o = Q + bh * (size_t)(N_ * E_);
            *(float4*)&o[(size_t)r0 * E_ + tc * 4]       = make_float4(v0[0], v0[1], v0[2], v0[3]);
            *(float4*)&o[(size_t)(r0 + 1) * E_ + tc * 4] = make_float4(v1[0], v1[1], v1[2], v1[3]);
        }
    } else if (p == 1) {
        if (h == 2) {      // f32 KT needed only by the L1 head
            #pragma unroll
            for (int j = 0; j < 4; ++j) {
                Ys[tc * 4 + j][tr * 2]     = v0[j];
                Ys[tc * 4 + j][tr * 2 + 1] = v1[j];
            }
            __syncthreads();
            const int e  = tid >> 2;
            const int n0 = (tid & 3) * 8;
            float* o = KT + bh * (size_t)(E_ * N_) + (size_t)e * N_ + rowbase + n0;
            float4 a, c;
            a.x = Ys[e][n0 + 0]; a.y = Ys[e][n0 + 1];
            a.z = Ys[e][n0 + 2]; a.w = Ys[e][n0 + 3];
            c.x = Ys[e][n0 + 4]; c.y = Ys[e][n0 + 5];
            c.z = Ys[e][n0 + 6]; c.w = Ys[e][n0 + 7];
            *(float4*)&o[0] = a;
            *(float4*)&o[4] = c;
        }
    } else {
        #pragma unroll
        for (int j = 0; j < 4; ++j) {
            Vst[tc * 4 + j][tr * 2]     = f2bf(v0[j]);
            Vst[tc * 4 + j][tr * 2 + 1] = f2bf(v1[j]);
        }
        __syncthreads();
        const int et = tid >> 6, g = (tid >> 4) & 3, li = tid & 15;
        u16x8 wv8 = *(const u16x8*)&Vst[et * 16 + li][g * 8];
        *(u16x8*)&VF[bh * (size_t)(N_ * E_)
                     + (size_t)((((tile * 4 + et) * 4 + g) * 16) + li) * 8] = wv8;
    }
}

// ---------------------------------------------------------------------------
// attn_partial (R9 body + XCD swizzle).
// grid = 2048: blk = inner*16 + slot; inner = qt*4 + kh; bh = slot2bh(slot).
// pid = bh*512 + qt*16 + kh*4 + w  (matches combine's base*16+p layout).
// ---------------------------------------------------------------------------
template <int HEAD>
__device__ __forceinline__ void mfma_logits32(
    int w, int kh, int lane, size_t bh, int qt, int q0, int pid,
    const unsigned short* __restrict__ QF,
    const unsigned short* __restrict__ KF,
    const float* __restrict__ qn2, const float* __restrict__ kn2,
    char* Pw, float* __restrict__ Mpart, float* __restrict__ Spart)
{
    const int g = lane >> 4, li = lane & 15;
    const int row0 = g * 4;
    const unsigned short* qfb = QF + bh * (N_ * E_) + (size_t)qt * 1024;
    const unsigned short* kfb = KF + bh * (N_ * E_);

    bf16x8 a0 = *(const bf16x8*)&qfb[(g * 16 + li) * 8];
    bf16x8 a1 = *(const bf16x8*)&qfb[((g + 4) * 16 + li) * 8];

    float qrow[4];
    if (HEAD == 1) {
        #pragma unroll
        for (int j = 0; j < 4; ++j) qrow[j] = rsqrtf(qn2[bh * N_ + q0 + row0 + j]);
    } else if (HEAD == 3) {
        #pragma unroll
        for (int j = 0; j < 4; ++j) qrow[j] = qn2[bh * N_ + q0 + row0 + j];
    }

    float lg[2][4];
    #pragma unroll
    for (int t = 0; t < 2; ++t) {
        const int kt = (kh * 4 + w) * 2 + t;
        const int m0 = kt * 16;
        bf16x8 b0 = *(const bf16x8*)&kfb[(size_t)((kt * 8 + g) * 16 + li) * 8];
        bf16x8 b1 = *(const bf16x8*)&kfb[(size_t)((kt * 8 + g + 4) * 16 + li) * 8];
        f32x4 acc = {0.f, 0.f, 0.f, 0.f};
        acc = __builtin_amdgcn_mfma_f32_16x16x32_bf16(a0, b0, acc, 0, 0, 0);
        acc = __builtin_amdgcn_mfma_f32_16x16x32_bf16(a1, b1, acc, 0, 0, 0);
        float kcol = 0.f, rk = 0.f;
        if (HEAD == 1) { kcol = kn2[bh * N_ + m0 + li]; rk = rsqrtf(kcol); }
        if (HEAD == 3) { kcol = kn2[bh * N_ + m0 + li]; }
        #pragma unroll
        for (int j = 0; j < 4; ++j) {
            float d = acc[j];
            if (HEAD == 0)      lg[t][j] = d * 0.125f;
            else if (HEAD == 1) lg[t][j] = d * qrow[j] * rk;
            else                lg[t][j] = -sqrtf(fmaxf(qrow[j] + kcol - 2.f * d, 0.f));
        }
    }

    float mx[4];
    #pragma unroll
    for (int j = 0; j < 4; ++j) {
        float m = fmaxf(lg[0][j], lg[1][j]);
        #pragma unroll
        for (int off = 1; off < 16; off <<= 1) m = fmaxf(m, __shfl_xor(m, off, 64));
        mx[j] = m;
    }

    float sm[4] = {0.f, 0.f, 0.f, 0.f};
    #pragma unroll
    for (int t = 0; t < 2; ++t) {
        #pragma unroll
        for (int j = 0; j < 4; ++j) {
            const int row = row0 + j;
            float pv = __expf(lg[t][j] - mx[j]);
            sm[j] += pv;
            const int byte = (row * 64 + (t * 16 + li) * 2) ^ ((row & 7) << 4);
            *(unsigned short*)(Pw + byte) = f2bf(pv);
        }
    }
    #pragma unroll
    for (int j = 0; j < 4; ++j) {
        float s = sm[j];
        #pragma unroll
        for (int off = 1; off < 16; off <<= 1) s += __shfl_xor(s, off, 64);
        if (li == 0) {
            Mpart[(size_t)pid * 16 + row0 + j] = mx[j];
            Spart[(size_t)pid * 16 + row0 + j] = s;
        }
    }
}

__global__ __launch_bounds__(256) void attn_partial(
    const float* __restrict__ Qf, const float* __restrict__ KT,
    const unsigned short* __restrict__ QF, const unsigned short* __restrict__ KF,
    const unsigned short* __restrict__ VF,
    const float* __restrict__ qn2, const float* __restrict__ kn2,
    float* __restrict__ Opart, float* __restrict__ Mpart,
    float* __restrict__ Spart)
{
    const int tid  = threadIdx.x;
    const int w    = tid >> 6;
    const int lane = tid & 63;
    const int slot  = blockIdx.x & 15;
    const int inner = blockIdx.x >> 4;     // 0..127
    const int kh = inner & 3;
    const int qt = inner >> 2;
    const int bhid = slot2bh(slot);
    const size_t bhs = (size_t)bhid;
    const int q0 = qt * 16;
    const int pid = bhid * 512 + qt * 16 + kh * 4 + w;

    __shared__ unsigned short Plds[4][512];
    __shared__ float q_lds[16][68];

    const int g = lane >> 4, li = lane & 15;
    char* Pw = (char*)&Plds[w][0];
    const int h = bhid & 3;

    if (h == 2) {
        {
            const int r = tid >> 4, c0 = (tid & 15) * 4;
            *(float4*)&q_lds[r][c0] =
                *(const float4*)&Qf[bhs * (N_ * E_) + (size_t)(q0 + r) * E_ + c0];
        }
        __syncthreads();

        const int half = lane >> 5;
        const int kloc = lane & 31;
        const int key  = kh * 128 + w * 32 + kloc;
        const float* kp = KT + bhs * (E_ * N_) + key;

        float acc[8];
        #pragma unroll
        for (int i = 0; i < 8; ++i) acc[i] = 0.f;

        #pragma unroll 4
        for (int ec = 0; ec < 16; ++ec) {
            float k0 = kp[(size_t)(ec * 4 + 0) * N_];
            float k1 = kp[(size_t)(ec * 4 + 1) * N_];
            float k2 = kp[(size_t)(ec * 4 + 2) * N_];
            float k3 = kp[(size_t)(ec * 4 + 3) * N_];
            #pragma unroll
            for (int i = 0; i < 8; ++i) {
                float4 q4 = *(const float4*)&q_lds[half * 8 + i][ec * 4];
                acc[i] += fabsf(k0 - q4.x) + fabsf(k1 - q4.y)
                        + fabsf(k2 - q4.z) + fabsf(k3 - q4.w);
            }
        }

        #pragma unroll
        for (int i = 0; i < 8; ++i) {
            const int row = half * 8 + i;
            float mn = acc[i];
            #pragma unroll
            for (int off = 1; off < 32; off <<= 1) mn = fminf(mn, __shfl_xor(mn, off, 64));
            float p = __expf(mn - acc[i]);
            float s = p;
            #pragma unroll
            for (int off = 1; off < 32; off <<= 1) s += __shfl_xor(s, off, 64);
            const int byte = (row * 64 + kloc * 2) ^ ((row & 7) << 4);
            *(unsigned short*)(Pw + byte) = f2bf(p);
            if (kloc == 0) {
                Mpart[(size_t)pid * 16 + row] = -mn;
                Spart[(size_t)pid * 16 + row] = s;
            }
        }
    } else if (h == 0) {
        mfma_logits32<0>(w, kh, lane, bhs, qt, q0, pid, QF, KF, qn2, kn2, Pw, Mpart, Spart);
    } else if (h == 1) {
        mfma_logits32<1>(w, kh, lane, bhs, qt, q0, pid, QF, KF, qn2, kn2, Pw, Mpart, Spart);
    } else {
        mfma_logits32<3>(w, kh, lane, bhs, qt, q0, pid, QF, KF, qn2, kn2, Pw, Mpart, Spart);
    }
    __syncthreads();

    {
        const int byte = (li * 64 + g * 16) ^ ((li & 7) << 4);
        bf16x8 pa = *(const bf16x8*)(Pw + byte);
        const int kb = kh * 4 + w;
        const unsigned short* vfb = VF + bhs * (N_ * E_);
        #pragma unroll
        for (int et = 0; et < 4; ++et) {
            f32x4 acc = {0.f, 0.f, 0.f, 0.f};
            bf16x8 vb = *(const bf16x8*)&vfb[
                (size_t)((((kb * 4 + et) * 4 + g) * 16) + li) * 8];
            acc = __builtin_amdgcn_mfma_f32_16x16x32_bf16(pa, vb, acc, 0, 0, 0);
            *(f32x4*)&Opart[(size_t)pid * 1024 + ((et * 4 + g) * 16 + li) * 4] = acc;
        }
    }
}

// ---------------------------------------------------------------------------
// combine (R9 body + XCD swizzle): blk = qt*16 + slot; bh = slot2bh(slot).
// Reads Opart written by attn blocks on the SAME XCD -> L2 hits.
// ---------------------------------------------------------------------------
__global__ __launch_bounds__(256) void combine_kernel(
    const float* __restrict__ Opart, const float* __restrict__ Mpart,
    const float* __restrict__ Spart, float* __restrict__ out)
{
    const int tid = threadIdx.x;
    const int slot = blockIdx.x & 15;
    const int qt   = blockIdx.x >> 4;
    const int bhid = slot2bh(slot);
    const int b = bhid >> 2, h = bhid & 3;
    const int base = (bhid * 32 + qt) * 16;

    __shared__ float ms[16][16], ss[16][16], wls[16][16];
    __shared__ float sginv[16];
    __shared__ float Ot[16][68];

    {
        const int p = tid >> 4, row = tid & 15;
        ms[p][row] = Mpart[(size_t)(base + p) * 16 + row];
        ss[p][row] = Spart[(size_t)(base + p) * 16 + row];
    }
    __syncthreads();
    {
        const int p = tid >> 4, row = tid & 15;
        float mg = ms[0][row];
        #pragma unroll
        for (int q = 1; q < 16; ++q) mg = fmaxf(mg, ms[q][row]);
        wls[p][row] = __expf(ms[p][row] - mg);
    }
    __syncthreads();
    if (tid < 16) {
        float s = 0.f;
        #pragma unroll
        for (int p = 0; p < 16; ++p) s += wls[p][tid] * ss[p][tid];
        sginv[tid] = 1.f / s;
    }
    __syncthreads();

    {
        const int et = tid >> 6, g = (tid >> 4) & 3, li = tid & 15;
        float o0 = 0.f, o1 = 0.f, o2 = 0.f, o3 = 0.f;
        const float* op = Opart + (size_t)base * 1024 + ((et * 4 + g) * 16 + li) * 4;
        #pragma unroll
        for (int p = 0; p < 16; ++p) {
            float4 v = *(const float4*)(op + (size_t)p * 1024);
            o0 = fmaf(wls[p][g * 4 + 0], v.x, o0);
            o1 = fmaf(wls[p][g * 4 + 1], v.y, o1);
            o2 = fmaf(wls[p][g * 4 + 2], v.z, o2);
            o3 = fmaf(wls[p][g * 4 + 3], v.w, o3);
        }
        Ot[g * 4 + 0][et * 16 + li] = o0 * sginv[g * 4 + 0];
        Ot[g * 4 + 1][et * 16 + li] = o1 * sginv[g * 4 + 1];
        Ot[g * 4 + 2][et * 16 + li] = o2 * sginv[g * 4 + 2];
        Ot[g * 4 + 3][et * 16 + li] = o3 * sginv[g * 4 + 3];
    }
    __syncthreads();
    {
        const int row = tid >> 4, e0 = (tid & 15) * 4;
        const int n = qt * 16 + row;
        *(float4*)&out[((size_t)b * N_ + n) * (H_ * E_) + h * E_ + e0] =
            *(const float4*)&Ot[row][e0];
    }
}

// ---------------------------------------------------------------------------
extern "C" void kernel_launch(void* const* d_in, const int* in_sizes, int n_in,
                              void* d_out, int out_size, void* d_ws, size_t ws_size,
                              hipStream_t stream)
{
    const float* x  = (const float*)d_in[0];
    const float* Wq = (const float*)d_in[1];
    const float* bq = (const float*)d_in[2];
    const float* Wk = (const float*)d_in[3];
    const float* bk = (const float*)d_in[4];
    const float* Wv = (const float*)d_in[5];
    const float* bv = (const float*)d_in[6];
    float* out = (float*)d_out;

    const size_t qkv = (size_t)B_ * H_ * N_ * E_;   // 524288
    float* Q     = (float*)d_ws;
    float* KT    = Q + qkv;
    float* qn2   = KT + qkv;
    float* kn2   = qn2 + (size_t)B_ * H_ * N_;
    float* Opart = kn2 + (size_t)B_ * H_ * N_;      // 8192 * 1024 f32 = 32 MB
    float* Mpart = Opart + (size_t)8192 * 1024;
    float* Spart = Mpart + (size_t)8192 * 16;
    unsigned short* QF = (unsigned short*)(Spart + (size_t)8192 * 16);
    unsigned short* KF = QF + qkv;
    unsigned short* VF = KF + qkv;

    proj_kernel<<<B_ * H_ * 3 * (N_ / 32), 256, 0, stream>>>(
        x, Wq, bq, Wk, bk, Wv, bv, Q, KT, qn2, kn2, QF, KF, VF);
    attn_partial<<<B_ * H_ * 32 * 4, 256, 0, stream>>>(
        Q, KT, QF, KF, VF, qn2, kn2, Opart, Mpart, Spart);
    combine_kernel<<<B_ * H_ * 32, 256, 0, stream>>>(Opart, Mpart, Spart, out);
}

// Round 21
// 50.570 us; speedup vs baseline: 1.1913x; 1.1670x over previous
//
#include <hip/hip_runtime.h>
#include <hip/hip_bf16.h>
#include <math.h>

#define B_   4
#define N_   512
#define DIN  256
#define E_   64
#define H_   4

typedef __attribute__((ext_vector_type(8))) short bf16x8;
typedef __attribute__((ext_vector_type(8))) unsigned short u16x8;
typedef __attribute__((ext_vector_type(4))) float f32x4;

__device__ __forceinline__ unsigned short f2bf(float f) {
    __hip_bfloat16 h = __float2bfloat16(f);
    return *reinterpret_cast<unsigned short*>(&h);
}
__device__ __forceinline__ float bf2f(unsigned short u) {
    unsigned int v = ((unsigned int)u) << 16;
    return __uint_as_float(v);
}
// slot (0..15) -> bh, XCD-locality perm: slot%8 = XCD, pairs (2s, 2s+1) per XCD
__device__ __forceinline__ int slot2bh(int slot) {
    return ((slot & 7) << 1) | (slot >> 3);
}

// ---------------------------------------------------------------------------
// Projection (R17/R20-identical).
// ---------------------------------------------------------------------------
__global__ __launch_bounds__(256) void proj_kernel(
    const float* __restrict__ x,
    const float* __restrict__ Wq, const float* __restrict__ bq,
    const float* __restrict__ Wk, const float* __restrict__ bk,
    const float* __restrict__ Wv, const float* __restrict__ bv,
    float* __restrict__ Q, float* __restrict__ KT,
    float* __restrict__ qn2, float* __restrict__ kn2,
    unsigned short* __restrict__ QF, unsigned short* __restrict__ KF,
    unsigned short* __restrict__ VF)
{
    const int tid = threadIdx.x;
    const int slot = blockIdx.x & 15;
    const int rest = blockIdx.x >> 4;      // 0..47
    const int tile = rest & 15;
    const int p    = rest >> 4;            // 0..2
    const int bhid = slot2bh(slot);
    const int h = bhid & 3;
    const int b = bhid >> 2;

    const float* W;
    const float* bias;
    if (p == 0)      { W = Wq; bias = bq; }
    else if (p == 1) { W = Wk; bias = bk; }
    else             { W = Wv; bias = bv; }
    W    += (size_t)h * DIN * E_;
    bias += h * E_;

    const int rowbase = tile * 32;
    const float* xb = x + ((size_t)b * N_ + rowbase) * DIN;

    __shared__ float XsT[64][34];
    __shared__ float Ws[64][64];
    __shared__ float Ys[64][33];
    __shared__ unsigned short Vst[64][48];

    const int tr = tid >> 4;
    const int tc = tid & 15;

    float acc[2][4];
    #pragma unroll
    for (int i = 0; i < 2; ++i)
        #pragma unroll
        for (int j = 0; j < 4; ++j) acc[i][j] = 0.f;

    for (int dc = 0; dc < DIN; dc += 64) {
        for (int l = tid; l < 2048; l += 256) {
            int r = l >> 6, d = l & 63;
            XsT[d][r] = xb[r * DIN + dc + d];
        }
        {
            const float4* Wg4 = (const float4*)(W + (size_t)dc * E_);
            #pragma unroll
            for (int i = 0; i < 4; ++i) ((float4*)Ws)[tid + i * 256] = Wg4[tid + i * 256];
        }
        __syncthreads();

        #pragma unroll 8
        for (int d = 0; d < 64; ++d) {
            float2 xv = *(const float2*)&XsT[d][tr * 2];
            float4 wv = *(const float4*)&Ws[d][tc * 4];
            acc[0][0] = fmaf(xv.x, wv.x, acc[0][0]);
            acc[0][1] = fmaf(xv.x, wv.y, acc[0][1]);
            acc[0][2] = fmaf(xv.x, wv.z, acc[0][2]);
            acc[0][3] = fmaf(xv.x, wv.w, acc[0][3]);
            acc[1][0] = fmaf(xv.y, wv.x, acc[1][0]);
            acc[1][1] = fmaf(xv.y, wv.y, acc[1][1]);
            acc[1][2] = fmaf(xv.y, wv.z, acc[1][2]);
            acc[1][3] = fmaf(xv.y, wv.w, acc[1][3]);
        }
        __syncthreads();
    }

    const size_t bh = (size_t)bhid;
    float4 bias4 = *(const float4*)&bias[tc * 4];
    float v0[4], v1[4];
    v0[0] = acc[0][0] + bias4.x; v0[1] = acc[0][1] + bias4.y;
    v0[2] = acc[0][2] + bias4.z; v0[3] = acc[0][3] + bias4.w;
    v1[0] = acc[1][0] + bias4.x; v1[1] = acc[1][1] + bias4.y;
    v1[2] = acc[1][2] + bias4.z; v1[3] = acc[1][3] + bias4.w;

    const int r0 = rowbase + tr * 2;

    if (p < 2) {
        float s0 = 0.f, s1 = 0.f;
        #pragma unroll
        for (int j = 0; j < 4; ++j) {
            s0 = fmaf(v0[j], v0[j], s0);
            s1 = fmaf(v1[j], v1[j], s1);
        }
        #pragma unroll
        for (int off = 1; off < 16; off <<= 1) {
            s0 += __shfl_xor(s0, off, 64);
            s1 += __shfl_xor(s1, off, 64);
        }
        if (tc == 0) {
            float* nrm = (p == 0) ? qn2 : kn2;
            nrm[bh * N_ + r0]     = s0;
            nrm[bh * N_ + r0 + 1] = s1;
        }
        unsigned short* f = ((p == 0) ? QF : KF) + bh * (size_t)(N_ * E_);
        const int t_ = r0 >> 4, li = r0 & 15;
        const int gg = tc >> 1, j0 = (tc & 1) * 4;
        ushort4 u0, u1;
        u0.x = f2bf(v0[0]); u0.y = f2bf(v0[1]); u0.z = f2bf(v0[2]); u0.w = f2bf(v0[3]);
        u1.x = f2bf(v1[0]); u1.y = f2bf(v1[1]); u1.z = f2bf(v1[2]); u1.w = f2bf(v1[3]);
        *(ushort4*)&f[(size_t)((t_ * 8 + gg) * 16 + li) * 8 + j0]       = u0;
        *(ushort4*)&f[(size_t)((t_ * 8 + gg) * 16 + li + 1) * 8 + j0]   = u1;
    }

    if (p == 0) {
        if (h == 2) {
            float* o = Q + bh * (size_t)(N_ * E_);
            *(float4*)&o[(size_t)r0 * E_ + tc * 4]       = make_float4(v0[0], v0[1], v0[2], v0[3]);
            *(float4*)&o[(size_t)(r0 + 1) * E_ + tc * 4] = make_float4(v1[0], v1[1], v1[2], v1[3]);
        }
    } else if (p == 1) {
        if (h == 2) {
            #pragma unroll
            for (int j = 0; j < 4; ++j) {
                Ys[tc * 4 + j][tr * 2]     = v0[j];
                Ys[tc * 4 + j][tr * 2 + 1] = v1[j];
            }
            __syncthreads();
            const int e  = tid >> 2;
            const int n0 = (tid & 3) * 8;
            float* o = KT + bh * (size_t)(E_ * N_) + (size_t)e * N_ + rowbase + n0;
            float4 a, c;
            a.x = Ys[e][n0 + 0]; a.y = Ys[e][n0 + 1];
            a.z = Ys[e][n0 + 2]; a.w = Ys[e][n0 + 3];
            c.x = Ys[e][n0 + 4]; c.y = Ys[e][n0 + 5];
            c.z = Ys[e][n0 + 6]; c.w = Ys[e][n0 + 7];
            *(float4*)&o[0] = a;
            *(float4*)&o[4] = c;
        }
    } else {
        #pragma unroll
        for (int j = 0; j < 4; ++j) {
            Vst[tc * 4 + j][tr * 2]     = f2bf(v0[j]);
            Vst[tc * 4 + j][tr * 2 + 1] = f2bf(v1[j]);
        }
        __syncthreads();
        const int et = tid >> 6, g = (tid >> 4) & 3, li = tid & 15;
        u16x8 wv8 = *(const u16x8*)&Vst[et * 16 + li][g * 8];
        *(u16x8*)&VF[bh * (size_t)(N_ * E_)
                     + (size_t)((((tile * 4 + et) * 4 + g) * 16) + li) * 8] = wv8;
    }
}

// ---------------------------------------------------------------------------
// attn_fused: grid = 16 slot x 32 qt = 512 blocks, 1024 thr (16 waves).
// Wave w owns keys [w*32, w*32+32) with the EXACT R17 wave body (VGPR ~48).
// Partials exchanged via LDS (bf16 O, f32 m/s); combine inlined after ONE
// barrier. No fences, no atomics, no global partial traffic, 2 blocks/CU.
// ---------------------------------------------------------------------------
__global__ __launch_bounds__(1024) void attn_fused(
    const float* __restrict__ Qf, const float* __restrict__ KT,
    const unsigned short* __restrict__ QF, const unsigned short* __restrict__ KF,
    const unsigned short* __restrict__ VF,
    const float* __restrict__ qn2, const float* __restrict__ kn2,
    float* __restrict__ out)
{
    const int tid  = threadIdx.x;
    const int w    = tid >> 6;             // 0..15
    const int lane = tid & 63;
    const int slot = blockIdx.x & 15;
    const int qt   = blockIdx.x >> 4;
    const int bhid = slot2bh(slot);
    const size_t bhs = (size_t)bhid;
    const int q0 = qt * 16;
    const int h = bhid & 3;

    __shared__ unsigned short Plds[16][512];       // per-wave [16 rows][32 keys]
    __shared__ float q_lds[16][68];
    __shared__ unsigned short OL[16][16][66];      // [wave][row][e] bf16 partials
    __shared__ float wmaxL[16][16];
    __shared__ float wsumL[16][16];
    __shared__ float wls[16][16];
    __shared__ float sginv[16];

    const int g = lane >> 4, li = lane & 15;
    char* Pw = (char*)&Plds[w][0];

    if (h == 2) {
        // ---- L1 head, f32 exact: wave w covers 32 keys; half-wave = 8 rows ----
        if (tid < 256) {
            const int r = tid >> 4, c0 = (tid & 15) * 4;
            *(float4*)&q_lds[r][c0] =
                *(const float4*)&Qf[bhs * (N_ * E_) + (size_t)(q0 + r) * E_ + c0];
        }
        __syncthreads();

        const int half = lane >> 5;
        const int kloc = lane & 31;
        const int key  = w * 32 + kloc;
        const float* kp = KT + bhs * (E_ * N_) + key;

        float acc[8];
        #pragma unroll
        for (int i = 0; i < 8; ++i) acc[i] = 0.f;

        #pragma unroll 4
        for (int ec = 0; ec < 16; ++ec) {
            float k0 = kp[(size_t)(ec * 4 + 0) * N_];
            float k1 = kp[(size_t)(ec * 4 + 1) * N_];
            float k2 = kp[(size_t)(ec * 4 + 2) * N_];
            float k3 = kp[(size_t)(ec * 4 + 3) * N_];
            #pragma unroll
            for (int i = 0; i < 8; ++i) {
                float4 q4 = *(const float4*)&q_lds[half * 8 + i][ec * 4];
                acc[i] += fabsf(k0 - q4.x) + fabsf(k1 - q4.y)
                        + fabsf(k2 - q4.z) + fabsf(k3 - q4.w);
            }
        }

        #pragma unroll
        for (int i = 0; i < 8; ++i) {
            const int row = half * 8 + i;
            float mn = acc[i];
            #pragma unroll
            for (int off = 1; off < 32; off <<= 1) mn = fminf(mn, __shfl_xor(mn, off, 64));
            float p = __expf(mn - acc[i]);
            float s = p;
            #pragma unroll
            for (int off = 1; off < 32; off <<= 1) s += __shfl_xor(s, off, 64);
            const int byte = (row * 64 + kloc * 2) ^ ((row & 7) << 4);
            *(unsigned short*)(Pw + byte) = f2bf(p);
            if (kloc == 0) {
                wmaxL[w][row] = -mn;
                wsumL[w][row] = s;
            }
        }
    } else {
        // ---- MFMA heads (R17 body, kt = w*2 + t) ----
        const int row0 = g * 4;
        const unsigned short* qfb = QF + bhs * (N_ * E_) + (size_t)qt * 1024;
        const unsigned short* kfb = KF + bhs * (N_ * E_);

        bf16x8 a0 = *(const bf16x8*)&qfb[(g * 16 + li) * 8];
        bf16x8 a1 = *(const bf16x8*)&qfb[((g + 4) * 16 + li) * 8];

        float qrow[4] = {0.f, 0.f, 0.f, 0.f};
        if (h == 1) {
            #pragma unroll
            for (int j = 0; j < 4; ++j) qrow[j] = rsqrtf(qn2[bhs * N_ + q0 + row0 + j]);
        } else if (h == 3) {
            #pragma unroll
            for (int j = 0; j < 4; ++j) qrow[j] = qn2[bhs * N_ + q0 + row0 + j];
        }

        float lg[2][4];
        #pragma unroll
        for (int t = 0; t < 2; ++t) {
            const int kt = w * 2 + t;
            const int m0 = kt * 16;
            bf16x8 b0 = *(const bf16x8*)&kfb[(size_t)((kt * 8 + g) * 16 + li) * 8];
            bf16x8 b1 = *(const bf16x8*)&kfb[(size_t)((kt * 8 + g + 4) * 16 + li) * 8];
            f32x4 acc = {0.f, 0.f, 0.f, 0.f};
            acc = __builtin_amdgcn_mfma_f32_16x16x32_bf16(a0, b0, acc, 0, 0, 0);
            acc = __builtin_amdgcn_mfma_f32_16x16x32_bf16(a1, b1, acc, 0, 0, 0);
            float kcol = 0.f, rk = 0.f;
            if (h == 1) { kcol = kn2[bhs * N_ + m0 + li]; rk = rsqrtf(kcol); }
            if (h == 3) { kcol = kn2[bhs * N_ + m0 + li]; }
            #pragma unroll
            for (int j = 0; j < 4; ++j) {
                float d = acc[j];
                if (h == 0)      lg[t][j] = d * 0.125f;
                else if (h == 1) lg[t][j] = d * qrow[j] * rk;
                else             lg[t][j] = -sqrtf(fmaxf(qrow[j] + kcol - 2.f * d, 0.f));
            }
        }

        float mx[4];
        #pragma unroll
        for (int j = 0; j < 4; ++j) {
            float m = fmaxf(lg[0][j], lg[1][j]);
            #pragma unroll
            for (int off = 1; off < 16; off <<= 1) m = fmaxf(m, __shfl_xor(m, off, 64));
            mx[j] = m;
        }

        float sm[4] = {0.f, 0.f, 0.f, 0.f};
        #pragma unroll
        for (int t = 0; t < 2; ++t) {
            #pragma unroll
            for (int j = 0; j < 4; ++j) {
                const int row = row0 + j;
                float pv = __expf(lg[t][j] - mx[j]);
                sm[j] += pv;
                const int byte = (row * 64 + (t * 16 + li) * 2) ^ ((row & 7) << 4);
                *(unsigned short*)(Pw + byte) = f2bf(pv);
            }
        }
        #pragma unroll
        for (int j = 0; j < 4; ++j) {
            float s = sm[j];
            #pragma unroll
            for (int off = 1; off < 16; off <<= 1) s += __shfl_xor(s, off, 64);
            if (li == 0) {
                wmaxL[w][row0 + j] = mx[j];
                wsumL[w][row0 + j] = s;
            }
        }
    }

    // ---- PV (wave-private P; no barrier needed before this) ----
    {
        const int byte = (li * 64 + g * 16) ^ ((li & 7) << 4);
        bf16x8 pa = *(const bf16x8*)(Pw + byte);
        const unsigned short* vfb = VF + bhs * (N_ * E_);
        #pragma unroll
        for (int et = 0; et < 4; ++et) {
            f32x4 acc = {0.f, 0.f, 0.f, 0.f};
            bf16x8 vb = *(const bf16x8*)&vfb[
                (size_t)((((w * 4 + et) * 4 + g) * 16) + li) * 8];
            acc = __builtin_amdgcn_mfma_f32_16x16x32_bf16(pa, vb, acc, 0, 0, 0);
            #pragma unroll
            for (int j = 0; j < 4; ++j)
                OL[w][g * 4 + j][et * 16 + li] = f2bf(acc[j]);
        }
    }
    __syncthreads();   // all 16 waves' partials + m/s visible

    // ---- inlined combine ----
    if (tid < 256) {
        const int p = tid >> 4, row = tid & 15;
        float mg = wmaxL[0][row];
        #pragma unroll
        for (int q = 1; q < 16; ++q) mg = fmaxf(mg, wmaxL[q][row]);
        wls[p][row] = __expf(wmaxL[p][row] - mg);
    }
    __syncthreads();
    if (tid < 16) {
        float s = 0.f;
        #pragma unroll
        for (int p = 0; p < 16; ++p) s += wls[p][tid] * wsumL[p][tid];
        sginv[tid] = 1.f / s;
    }
    __syncthreads();
    {
        const int row = tid >> 6, e = tid & 63;
        float o = 0.f;
        #pragma unroll
        for (int p = 0; p < 16; ++p)
            o = fmaf(wls[p][row], bf2f(OL[p][row][e]), o);
        const int b = bhid >> 2;
        const int n = q0 + row;
        out[((size_t)b * N_ + n) * (H_ * E_) + h * E_ + e] = o * sginv[row];
    }
}

// ---------------------------------------------------------------------------
extern "C" void kernel_launch(void* const* d_in, const int* in_sizes, int n_in,
                              void* d_out, int out_size, void* d_ws, size_t ws_size,
                              hipStream_t stream)
{
    const float* x  = (const float*)d_in[0];
    const float* Wq = (const float*)d_in[1];
    const float* bq = (const float*)d_in[2];
    const float* Wk = (const float*)d_in[3];
    const float* bk = (const float*)d_in[4];
    const float* Wv = (const float*)d_in[5];
    const float* bv = (const float*)d_in[6];
    float* out = (float*)d_out;

    const size_t qkv = (size_t)B_ * H_ * N_ * E_;   // 524288
    float* Q   = (float*)d_ws;
    float* KT  = Q + qkv;
    float* qn2 = KT + qkv;
    float* kn2 = qn2 + (size_t)B_ * H_ * N_;
    unsigned short* QF = (unsigned short*)(kn2 + (size_t)B_ * H_ * N_);
    unsigned short* KF = QF + qkv;
    unsigned short* VF = KF + qkv;

    proj_kernel<<<B_ * H_ * 3 * (N_ / 32), 256, 0, stream>>>(
        x, Wq, bq, Wk, bk, Wv, bv, Q, KT, qn2, kn2, QF, KF, VF);
    attn_fused<<<B_ * H_ * 32, 1024, 0, stream>>>(
        Q, KT, QF, KF, VF, qn2, kn2, out);
}